// Round 1
// baseline (16501.389 us; speedup 1.0000x reference)
//
#include <hip/hip_runtime.h>

// ---------------------------------------------------------------------------
// Problem: 2-layer GRU LM forward. B=32, T=256, V=32000, H=512, L=2, ALPHA=1.
// Inputs: x[B,T] i32, emb[V,H] f32, Wih[L,3H,H], Whh[L,3H,H], bih[L,3H],
//         bhh[L,3H], Wout[V,H], bout[V]. Output: logits [B,T,V] f32.
// Quirk (faithful to reference): one hidden tensor threads through BOTH
// layers; layer1 uses h1 as both its input x and its hidden h.
// ---------------------------------------------------------------------------

#define B_ 32
#define T_ 256
#define V_ 32000
#define H_ 512
#define H3_ 1536

typedef __bf16 bf16x8 __attribute__((ext_vector_type(8)));
typedef float f32x4v __attribute__((ext_vector_type(4)));
typedef unsigned short u16x8 __attribute__((ext_vector_type(8)));

// ---------------------------------------------------------------- grid barrier
__device__ __forceinline__ void grid_sync(int* bar, int nwg) {
  __syncthreads();
  if (threadIdx.x == 0) {
    unsigned int* cnt = (unsigned int*)bar;
    unsigned int* gen = (unsigned int*)((char*)bar + 64);
    unsigned int g = __hip_atomic_load(gen, __ATOMIC_RELAXED, __HIP_MEMORY_SCOPE_AGENT);
    unsigned int arrived =
        __hip_atomic_fetch_add(cnt, 1u, __ATOMIC_ACQ_REL, __HIP_MEMORY_SCOPE_AGENT);
    if (arrived == (unsigned int)(nwg - 1)) {
      __hip_atomic_store(cnt, 0u, __ATOMIC_RELAXED, __HIP_MEMORY_SCOPE_AGENT);
      __hip_atomic_fetch_add(gen, 1u, __ATOMIC_RELEASE, __HIP_MEMORY_SCOPE_AGENT);
    } else {
      while (__hip_atomic_load(gen, __ATOMIC_ACQUIRE, __HIP_MEMORY_SCOPE_AGENT) == g) {
        __builtin_amdgcn_s_sleep(2);
      }
    }
  }
  __syncthreads();
}

// ---------------------------------------------------------------- small utils
__global__ void k_cast_bf16(const float* __restrict__ in, __bf16* __restrict__ out, int n) {
  for (int i = blockIdx.x * 256 + threadIdx.x; i < n; i += gridDim.x * 256)
    out[i] = (__bf16)in[i];
}

// E[bt][k] = bf16(emb[x[bt]][k]); bt = b*T + t  (x is [B,T] row-major)
__global__ void k_gather(const int* __restrict__ x, const float* __restrict__ emb,
                         __bf16* __restrict__ E) {
  int bt = blockIdx.x;
  int row = x[bt];
  const float* src = emb + (size_t)row * H_;
  __bf16* dst = E + (size_t)bt * H_;
  for (int k = threadIdx.x; k < H_; k += 256) dst[k] = (__bf16)src[k];
}

// ------------------------------------------------------------------ MFMA GEMM
// C[M,N] f32 = A[M,K]bf16 . B[N,K]bf16^T + bias[N].  Both operands K-major.
// BM=BN=128, BK=32. 4 waves, each 64x64 via 4x4 tiles of 16x16x32 MFMA.
// Frag layouts (verified, learn_hip m89/m91): A/B: lane holds row (lane&15),
// k = (lane>>4)*8 + j.  D: col = lane&15, row = (lane>>4)*4 + reg.
__global__ __launch_bounds__(256) void k_gemm_bf16(
    const __bf16* __restrict__ A, const __bf16* __restrict__ B,
    const float* __restrict__ bias, float* __restrict__ C, int M, int N, int K) {
  __shared__ __align__(16) __bf16 Alds[128 * 40];  // +8 pad: conflict-free b128
  __shared__ __align__(16) __bf16 Blds[128 * 40];
  const int tid = threadIdx.x;
  const int lane = tid & 63;
  const int wave = tid >> 6;
  const int lm = lane & 15;
  const int quad = lane >> 4;
  const int wrow = (wave >> 1) * 64;
  const int wcol = (wave & 1) * 64;
  const int m0 = blockIdx.y * 128;
  const int n0 = blockIdx.x * 128;
  const int srow = tid >> 2;          // 0..63
  const int schunk = (tid & 3) * 8;   // element offset 0,8,16,24

  f32x4v acc[4][4] = {};

  for (int k0 = 0; k0 < K; k0 += 32) {
    __syncthreads();
#pragma unroll
    for (int p = 0; p < 128; p += 64) {
      int r = srow + p;
      *(u16x8*)&Alds[r * 40 + schunk] =
          *(const u16x8*)&A[(size_t)(m0 + r) * K + k0 + schunk];
      *(u16x8*)&Blds[r * 40 + schunk] =
          *(const u16x8*)&B[(size_t)(n0 + r) * K + k0 + schunk];
    }
    __syncthreads();
    bf16x8 af[4], bfv[4];
#pragma unroll
    for (int i = 0; i < 4; ++i)
      af[i] = *(const bf16x8*)&Alds[(wrow + i * 16 + lm) * 40 + quad * 8];
#pragma unroll
    for (int jj = 0; jj < 4; ++jj)
      bfv[jj] = *(const bf16x8*)&Blds[(wcol + jj * 16 + lm) * 40 + quad * 8];
#pragma unroll
    for (int i = 0; i < 4; ++i)
#pragma unroll
      for (int jj = 0; jj < 4; ++jj)
        acc[i][jj] = __builtin_amdgcn_mfma_f32_16x16x32_bf16(af[i], bfv[jj],
                                                             acc[i][jj], 0, 0, 0);
  }

#pragma unroll
  for (int i = 0; i < 4; ++i) {
    int mbase = m0 + wrow + i * 16 + quad * 4;
#pragma unroll
    for (int jj = 0; jj < 4; ++jj) {
      int n = n0 + wcol + jj * 16 + lm;
      float bv = bias[n];
#pragma unroll
      for (int r = 0; r < 4; ++r)
        C[(size_t)(mbase + r) * N + n] = acc[i][jj][r] + bv;
    }
  }
}

// ------------------------------------------------------------------ GRU scan
// Persistent cooperative-style kernel, 64 WGs x 256 threads, co-resident on
// 256 CUs (grid << CU count). Each WG owns 8 j-columns; thread = (b, jl).
// Per step: phase L0 (gh0 dots + gates) -> grid_sync -> phase L1 -> grid_sync.
#define FMA4(acc, h4, w4)                                                     \
  acc = fmaf((h4).x, (w4).x,                                                  \
        fmaf((h4).y, (w4).y, fmaf((h4).z, (w4).z, fmaf((h4).w, (w4).w, acc))))

__global__ __launch_bounds__(256) void k_scan(
    const float* __restrict__ gi0,   // [B*T][3H], bt = b*T+t (bih0 included)
    const float* __restrict__ Whh0,  // [3H][H]
    const float* __restrict__ Wih1,  // [3H][H]
    const float* __restrict__ Whh1,  // [3H][H]
    const float* __restrict__ bhh0, const float* __restrict__ bih1,
    const float* __restrict__ bhh1,
    float* __restrict__ h_a,   // [B][H] carry (h_prev / h2)
    float* __restrict__ h_b,   // [B][H] h1
    __bf16* __restrict__ outs, // [B*T][H]
    int* __restrict__ bar) {
  __shared__ __align__(16) float h_lds[32 * 260];  // half of h, stride-pad +4
  const int tid = threadIdx.x;
  const int b = tid & 31;
  const int jl = tid >> 5;                // 0..7
  const int j = blockIdx.x * 8 + jl;      // 0..511
  const int nwg = gridDim.x;

  // h0 = 0 (ws is poisoned 0xAA each call: zero it ourselves)
  h_a[blockIdx.x * 256 + tid] = 0.f;
  grid_sync(bar, nwg);

  for (int t = 0; t < T_; ++t) {
    // ---------------- layer 0: gh0 = h_prev @ Whh0^T ----------------
    {
      float ar = 0.f, az = 0.f, an = 0.f;
#pragma unroll
      for (int half = 0; half < 2; ++half) {
        __syncthreads();
        for (int i = tid; i < 2048; i += 256) {  // 32 rows x 64 float4
          int row = i >> 6, c = i & 63;
          *(float4*)&h_lds[row * 260 + c * 4] =
              *(const float4*)&h_a[row * H_ + half * 256 + c * 4];
        }
        __syncthreads();
        const float4* wr = (const float4*)(Whh0 + (size_t)j * H_ + half * 256);
        const float4* wz = (const float4*)(Whh0 + (size_t)(j + 512) * H_ + half * 256);
        const float4* wn = (const float4*)(Whh0 + (size_t)(j + 1024) * H_ + half * 256);
        const float4* hq = (const float4*)&h_lds[b * 260];
#pragma unroll 4
        for (int kq = 0; kq < 64; ++kq) {
          float4 h4 = hq[kq];
          float4 w1 = wr[kq], w2 = wz[kq], w3 = wn[kq];
          FMA4(ar, h4, w1);
          FMA4(az, h4, w2);
          FMA4(an, h4, w3);
        }
      }
      int bt = b * T_ + t;
      float ir = gi0[(size_t)bt * H3_ + j];
      float iz = gi0[(size_t)bt * H3_ + 512 + j];
      float inn = gi0[(size_t)bt * H3_ + 1024 + j];
      float hr = ar + bhh0[j];
      float hz = az + bhh0[512 + j];
      float hn = an + bhh0[1024 + j];
      float rg = 1.f / (1.f + expf(-(ir + hr)));
      float zg = 1.f / (1.f + expf(-(iz + hz)));
      float ng = tanhf(inn + rg * hn);
      float hp = h_a[b * H_ + j];
      h_b[b * H_ + j] = (1.f - zg) * ng + zg * hp;
    }
    grid_sync(bar, nwg);
    // ---------------- layer 1: x = h = h1 (faithful quirk) ----------------
    {
      float air = 0.f, aiz = 0.f, ain = 0.f, ahr = 0.f, ahz = 0.f, ahn = 0.f;
#pragma unroll
      for (int half = 0; half < 2; ++half) {
        __syncthreads();
        for (int i = tid; i < 2048; i += 256) {
          int row = i >> 6, c = i & 63;
          *(float4*)&h_lds[row * 260 + c * 4] =
              *(const float4*)&h_b[row * H_ + half * 256 + c * 4];
        }
        __syncthreads();
        const float4* wir = (const float4*)(Wih1 + (size_t)j * H_ + half * 256);
        const float4* wiz = (const float4*)(Wih1 + (size_t)(j + 512) * H_ + half * 256);
        const float4* win = (const float4*)(Wih1 + (size_t)(j + 1024) * H_ + half * 256);
        const float4* whr = (const float4*)(Whh1 + (size_t)j * H_ + half * 256);
        const float4* whz = (const float4*)(Whh1 + (size_t)(j + 512) * H_ + half * 256);
        const float4* whn = (const float4*)(Whh1 + (size_t)(j + 1024) * H_ + half * 256);
        const float4* hq = (const float4*)&h_lds[b * 260];
#pragma unroll 2
        for (int kq = 0; kq < 64; ++kq) {
          float4 h4 = hq[kq];
          FMA4(air, h4, wir[kq]);
          FMA4(aiz, h4, wiz[kq]);
          FMA4(ain, h4, win[kq]);
          FMA4(ahr, h4, whr[kq]);
          FMA4(ahz, h4, whz[kq]);
          FMA4(ahn, h4, whn[kq]);
        }
      }
      float ir = air + bih1[j];
      float iz = aiz + bih1[512 + j];
      float inn = ain + bih1[1024 + j];
      float hr = ahr + bhh1[j];
      float hz = ahz + bhh1[512 + j];
      float hn = ahn + bhh1[1024 + j];
      float rg = 1.f / (1.f + expf(-(ir + hr)));
      float zg = 1.f / (1.f + expf(-(iz + hz)));
      float ng = tanhf(inn + rg * hn);
      float h1v = h_b[b * H_ + j];
      float h2 = (1.f - zg) * ng + zg * h1v;
      h_a[b * H_ + j] = h2;
      outs[(size_t)(b * T_ + t) * H_ + j] = (__bf16)h2;
    }
    grid_sync(bar, nwg);
  }
}

// ---------------------------------------------------------------------- host
extern "C" void kernel_launch(void* const* d_in, const int* in_sizes, int n_in,
                              void* d_out, int out_size, void* d_ws, size_t ws_size,
                              hipStream_t stream) {
  const int* x = (const int*)d_in[0];
  const float* emb = (const float*)d_in[1];
  const float* Wih = (const float*)d_in[2];
  const float* Whh = (const float*)d_in[3];
  const float* bih = (const float*)d_in[4];
  const float* bhh = (const float*)d_in[5];
  const float* Wout = (const float*)d_in[6];
  const float* bout = (const float*)d_in[7];
  float* out = (float*)d_out;
  char* ws = (char*)d_ws;

  // workspace layout (all offsets 256B-aligned), total ~97 MB
  const size_t o_E = 0;                                  // 8192*512 bf16 = 8 MB
  const size_t o_Wih0b = o_E + (size_t)8192 * 512 * 2;   // 1536*512 bf16
  const size_t o_Woutb = o_Wih0b + (size_t)1536 * 512 * 2;  // 32000*512 bf16
  const size_t o_gi0 = o_Woutb + (size_t)32000 * 512 * 2;   // 8192*1536 f32
  const size_t o_outs = o_gi0 + (size_t)8192 * 1536 * 4;    // 8192*512 bf16
  const size_t o_ha = o_outs + (size_t)8192 * 512 * 2;      // 32*512 f32
  const size_t o_hb = o_ha + (size_t)32 * 512 * 4;
  const size_t o_bar = o_hb + (size_t)32 * 512 * 4;

  __bf16* E = (__bf16*)(ws + o_E);
  __bf16* Wih0b = (__bf16*)(ws + o_Wih0b);
  __bf16* Woutb = (__bf16*)(ws + o_Woutb);
  float* gi0 = (float*)(ws + o_gi0);
  __bf16* outs = (__bf16*)(ws + o_outs);
  float* h_a = (float*)(ws + o_ha);
  float* h_b = (float*)(ws + o_hb);
  int* bar = (int*)(ws + o_bar);

  hipMemsetAsync(bar, 0, 256, stream);

  // embeddings gather + bf16 casts of Wih0 and Wout
  k_gather<<<B_ * T_, 256, 0, stream>>>(x, emb, E);
  k_cast_bf16<<<2048, 256, 0, stream>>>(Wih, Wih0b, H3_ * H_);
  k_cast_bf16<<<8192, 256, 0, stream>>>(Wout, Woutb, V_ * H_);

  // gi0 = E @ Wih0^T + bih0   [8192 x 1536]
  k_gemm_bf16<<<dim3(H3_ / 128, (B_ * T_) / 128), 256, 0, stream>>>(
      E, Wih0b, bih, gi0, B_ * T_, H3_, H_);

  // sequential 256-step scan (persistent, 64 WGs, grid barrier)
  k_scan<<<64, 256, 0, stream>>>(gi0, Whh, Wih + (size_t)H3_ * H_,
                                 Whh + (size_t)H3_ * H_, bhh, bih + H3_,
                                 bhh + H3_, h_a, h_b, outs, bar);

  // logits = outs @ Wout^T + bout   [8192 x 32000] -> d_out
  k_gemm_bf16<<<dim3(V_ / 128, (B_ * T_) / 128), 256, 0, stream>>>(
      outs, Woutb, bout, out, B_ * T_, V_, H_);
}